// Round 11
// baseline (6257.071 us; speedup 1.0000x reference)
//
#include <hip/hip_runtime.h>
#include <hip/hip_bf16.h>

// ---------------------------------------------------------------------------
// 2-layer LSTM (B=256,S=512,E=128,H=256) + LayerNorm + projection.
// Round 11: gate-split scan. 32 WGs: WG (bgi = bid&15, hf = bid>>4) computes
// hidden units j in [128*hf, 128*hf+128) for batch group bgi (16 cols).
// Per wave: 4 tiles (i,f,g,o of its j-range) x 8 p = 32 weight frags =
// 128 regs, ALL register-resident -> zero LDS weight stream (was 147KB/step).
// Cell VALU halves (4 elems/lane). WG pair exchanges h-halves (4KB each)
// per step via agent-scope atomics + monotonic flags (parity dbuf slots).
// 96KB dummy LDS forces 1 WG/CU -> 32 active CUs. Flags zeroed per launch.
// Math identical to round 9 (passed, absmax 0.0156).
// ---------------------------------------------------------------------------

typedef unsigned short u16;
typedef unsigned int   u32;
typedef unsigned long long u64;
using short8 = __attribute__((ext_vector_type(8))) short;
using f32x4  = __attribute__((ext_vector_type(4))) float;

#define NB 256
#define NS 512
#define NE 128
#define NH 256
#define NG 1024  // 4*H

#define XLDS 98304   // 96KB dummy alloc: forces 1 WG/CU (only 16KB used: h dbuf)

#define L2E     1.4426950408889634f
#define TWO_L2E 2.8853900817779268f

__device__ __forceinline__ u16 f2b(float x) {
  __hip_bfloat16 h = __float2bfloat16(x);
  return __builtin_bit_cast(u16, h);
}
__device__ __forceinline__ float b2f(u16 u) {
  return __builtin_bit_cast(float, (u32)u << 16);
}
__device__ __forceinline__ float ex2(float x)  { return __builtin_amdgcn_exp2f(x); }
__device__ __forceinline__ float ex2n(float x) { return __builtin_amdgcn_exp2f(-x); }
__device__ __forceinline__ float rcpa(float x) { return __builtin_amdgcn_rcpf(x); }

// ---------------- prep: fp32 weights -> bf16 (exp2-prescaled), biases ------
__global__ __launch_bounds__(256) void prep_weights(
    const float* Wih0, const float* Whh0, const float* bih0, const float* bhh0,
    const float* Wih1, const float* Whh1, const float* bih1, const float* bhh1,
    u16* wih0b, u16* whh0b, u16* wih1b, u16* whh1b, float* bc0, float* bc1) {
  int stride = gridDim.x * blockDim.x;
  int tid = blockIdx.x * blockDim.x + threadIdx.x;
  for (int i = tid; i < NG * NE; i += stride) {
    float s = (((i >> 7) >> 8) == 2) ? TWO_L2E : L2E;
    wih0b[i] = f2b(Wih0[i] * s);
  }
  for (int i = tid; i < NG * NH; i += stride) {
    float s = (((i >> 8) >> 8) == 2) ? TWO_L2E : L2E;
    whh0b[i] = f2b(Whh0[i] * s);
    wih1b[i] = f2b(Wih1[i] * s);
    whh1b[i] = f2b(Whh1[i] * s);
  }
  for (int i = tid; i < NG; i += stride) {
    float s = ((i >> 8) == 2) ? TWO_L2E : L2E;
    bc0[i] = (bih0[i] + bhh0[i]) * s;
    bc1[i] = (bih1[i] + bhh1[i]) * s;
  }
}

// ---------------- flag zeroing (per launch; replay-deterministic) ----------
__global__ __launch_bounds__(256) void zero_flags(u32* f, int n) {
  int i = blockIdx.x * 256 + threadIdx.x;
  if (i < n) f[i] = 0;
}

// ---------------- embedding gather for steps [t0, t0+T) -------------------
__global__ __launch_bounds__(256) void embed_chunk(const int* __restrict__ x,
                                                   const float* __restrict__ emb,
                                                   u16* __restrict__ ebuf, int t0) {
  int gid = blockIdx.x * 256 + threadIdx.x;
  int d4 = gid & 31;
  int sb = gid >> 5;                            // sl*B + b
  int b  = sb & (NB - 1);
  int sl = sb >> 8;
  int tok = x[b * NS + (t0 + sl)];              // x is [B][S]
  float4 v = make_float4(0.f, 0.f, 0.f, 0.f);
  if (tok != 0) v = *(const float4*)(emb + (size_t)tok * NE + d4 * 4);
  ushort4 o;
  o.x = f2b(v.x); o.y = f2b(v.y); o.z = f2b(v.z); o.w = f2b(v.w);
  *(ushort4*)(ebuf + (size_t)sb * NE + d4 * 4) = o;
}

// ---------------- xp GEMM: writes scan-fragment layout (unchanged) ---------
//   e = (((t*16+bgrp)*8+ws)*8+mts)*256 + (his*16+lo)*4 + rs
template <int K>
__global__ __launch_bounds__(256) void xp_gemm(const u16* __restrict__ A,
                                               const u16* __restrict__ W,
                                               const float* __restrict__ bias,
                                               u16* __restrict__ Cout) {
  __shared__ __align__(16) char lds[2 * 128 * 80];
  char* Asm = lds;
  char* Bsm = lds + 128 * 80;
  int tid = threadIdx.x;
  int w = tid >> 6, l = tid & 63;
  int hi = l >> 4, lo = l & 15;
  int mblk = blockIdx.x >> 3, nblk = blockIdx.x & 7;
  size_t arow0 = (size_t)mblk * 128;
  int g0 = nblk * 128;
  int wm = (w >> 1) * 64, wn = (w & 1) * 64;
  f32x4 acc[4][4] = {};
  int r = tid >> 1, cp = tid & 1;

  for (int k0 = 0; k0 < K; k0 += 32) {
    int4 a0 = *(const int4*)(A + (arow0 + r) * K + k0 + cp * 16);
    int4 a1 = *(const int4*)(A + (arow0 + r) * K + k0 + cp * 16 + 8);
    int4 b0 = *(const int4*)(W + (size_t)(g0 + r) * K + k0 + cp * 16);
    int4 b1 = *(const int4*)(W + (size_t)(g0 + r) * K + k0 + cp * 16 + 8);
    *(int4*)(Asm + r * 80 + cp * 32)      = a0;
    *(int4*)(Asm + r * 80 + cp * 32 + 16) = a1;
    *(int4*)(Bsm + r * 80 + cp * 32)      = b0;
    *(int4*)(Bsm + r * 80 + cp * 32 + 16) = b1;
    __syncthreads();
    short8 af[4], bfr[4];
#pragma unroll
    for (int mt = 0; mt < 4; ++mt)
      af[mt] = *(const short8*)(Asm + (wm + mt * 16 + lo) * 80 + hi * 16);
#pragma unroll
    for (int nt = 0; nt < 4; ++nt)
      bfr[nt] = *(const short8*)(Bsm + (wn + nt * 16 + lo) * 80 + hi * 16);
#pragma unroll
    for (int mt = 0; mt < 4; ++mt)
#pragma unroll
      for (int nt = 0; nt < 4; ++nt)
        acc[mt][nt] = __builtin_amdgcn_mfma_f32_16x16x32_bf16(af[mt], bfr[nt], acc[mt][nt], 0, 0, 0);
    __syncthreads();
  }
#pragma unroll
  for (int nt = 0; nt < 4; ++nt) {
    int gc = g0 + wn + nt * 16 + lo;
    float bv = bias[gc];
    int ws_ = (gc >> 4) & 7, mts = gc >> 7, his = (gc >> 2) & 3, rs = gc & 3;
    size_t gbase = ((size_t)(ws_ * 8 + mts) << 8) + (size_t)(his * 16) * 4 + rs;
#pragma unroll
    for (int mt = 0; mt < 4; ++mt) {
      size_t row = arow0 + wm + mt * 16 + hi * 4;
#pragma unroll
      for (int rr = 0; rr < 4; ++rr) {
        size_t rw = row + rr;
        int t = (int)(rw >> 8), ba = (int)(rw & 255);
        size_t e = ((size_t)(t * 16 + (ba >> 4)) << 14) + gbase + (size_t)(ba & 15) * 4;
        Cout[e] = f2b(acc[mt][nt][rr] + bv);
      }
    }
  }
}

// ---------------- LSTM scan: gate-split, 32 WGs ----------------------------
// WG (bgi = bid&15, hf = bid>>4): j in [128hf, 128hf+128), batch [16bgi,+16).
// Wave w tiles tau(q) = 8*(2q+hf)+w, q=0..3 = gates i,f,g,o for its 16 j's.
// Weights all-reg (wfv[4][8] = 128 VGPRs). h full (both halves) staged in
// LDS dbuf (2x8KB at offset 0, sigma layout, R4-verified). Per step:
// GEMV(8p x 4q MFMA) -> cell(4 elems) -> own-half: LDS write + agent store
// to exchange slot [bgi][t&1][hf] -> threadfence -> barrier -> tid0: flag
// release + poll partner flag -> barrier -> read partner 4KB (agent), LDS
// write -> barrier -> next step. Monotonic flags; parity slots safe (slot
// reuse at t+2 is ordered behind partner's flag >= t+2).
template <bool STORE_H>
__global__ __attribute__((amdgpu_flat_work_group_size(512, 512),
                          amdgpu_waves_per_eu(2, 2)))
void lstm_scan(const u16* __restrict__ xp,
               const u16* __restrict__ whh,
               u16* __restrict__ h_out,
               float* __restrict__ h_state,
               float* __restrict__ c_state,
               int T, int first,
               char* __restrict__ xbuf, u32* __restrict__ flags) {
  extern __shared__ __align__(16) char smem[];   // h dbuf: 2 x 8192 used
  int tid = threadIdx.x;
  int w = tid >> 6, l = tid & 63;
  int hi = l >> 4, lo = l & 15;
  int bid = blockIdx.x;
  int bgi = bid & 15, hf = bid >> 4;
  int bg = bgi * 16;

  // ---- weights: 4 tiles x 8 p, all in registers ----
  short8 wfv[4][8];
#pragma unroll
  for (int q = 0; q < 4; ++q) {
    int tau = 8 * (2 * q + hf) + w;
#pragma unroll
    for (int p = 0; p < 8; ++p)
      wfv[q][p] = *(const short8*)(whh + (size_t)(16 * tau + lo) * NH + p * 32 + hi * 8);
  }

  // ---- init h (full, LDS buffer 0) and c (own half, regs) ----
  float c[4];
  if (first) {
    for (int i = tid; i < 16 * NH / 2; i += 512) ((u32*)smem)[i] = 0;
#pragma unroll
    for (int r = 0; r < 4; ++r) c[r] = 0.0f;
  } else {
    for (int i = tid; i < 16 * NH; i += 512) {
      int b = i >> 8, k = i & 255;
      int p = k >> 5, hp = (k >> 3) & 3, kp = k & 7;
      int xx = hp * 16 + b;
      u16 hb = f2b(h_state[(size_t)(bg + b) * NH + k]);
      *(u16*)(smem + p * 1024 + (xx ^ ((xx >> 3) & 7)) * 16 + kp * 2) = hb;
    }
#pragma unroll
    for (int r = 0; r < 4; ++r) {
      int j = 128 * hf + 16 * w + 4 * hi + r;
      c[r] = c_state[(size_t)(bg + lo) * NH + j];
    }
  }
  __syncthreads();

  // ---- step-invariant offsets ----
  int rdoff = (l ^ ((l >> 3) & 7)) * 16;               // bfrag read
  int xx = (2 * (w & 1) + (hi >> 1)) * 16 + lo;
  int sxx = (xx ^ ((xx >> 3) & 7)) * 16 + 8 * (hi & 1);
  int wroff_own = (4 * hf + (w >> 1)) * 1024 + sxx;     // own half LDS write
  int wroff_par = (4 * (1 - hf) + (w >> 1)) * 1024 + sxx;
  int xoff = (w >> 1) * 1024 + sxx;                     // offset in 4KB block
  char* xb_self[2]; char* xb_par[2];
#pragma unroll
  for (int par = 0; par < 2; ++par) {
    xb_self[par] = xbuf + ((size_t)((bgi * 2 + par) * 2 + hf)) * 4096;
    xb_par[par]  = xbuf + ((size_t)((bgi * 2 + par) * 2 + (1 - hf))) * 4096;
  }
  u32* flag_self = flags + (bgi * 2 + hf) * 16;        // 64B stride
  u32* flag_par  = flags + (bgi * 2 + (1 - hf)) * 16;

  // STORE_H writeback (hf==0 WG, full h): thread -> (batch bq, k-chunk kc)
  int bq = tid >> 5, kc = tid & 31;
  int xw = (kc & 3) * 16 + bq;
  int wboff = (kc >> 2) * 1024 + (xw ^ ((xw >> 3) & 7)) * 16;
  size_t wb_glob = (size_t)(bg + bq) * NH + kc * 8;

  // xp fragment pointer (layout unchanged; this WG reads mts = 2q+hf)
  const u16* xpp = xp + (size_t)(bgi * 8 + w) * 2048 + (size_t)l * 4;
  ushort4 xq[4];
#pragma unroll
  for (int q = 0; q < 4; ++q) xq[q] = *(const ushort4*)(xpp + (2 * q + hf) * 256);

  f32x4 acc[4];
  for (int t = 0; t < T; ++t) {
    int rbase = (t & 1) << 13;        // read buffer (h_{t-1})
    int wbbase = 8192 - rbase;        // write buffer (h_t)
#pragma unroll
    for (int q = 0; q < 4; ++q) {
      f32x4 a;
      a[0] = b2f(xq[q].x); a[1] = b2f(xq[q].y);
      a[2] = b2f(xq[q].z); a[3] = b2f(xq[q].w);
      acc[q] = a;
    }
    xpp += 262144;                    // next t (overrun lands in iobuf: safe)
#pragma unroll
    for (int q = 0; q < 4; ++q) xq[q] = *(const ushort4*)(xpp + (2 * q + hf) * 256);
    // GEMV: 8 k-slots x 4 gate-tiles
#pragma unroll
    for (int p = 0; p < 8; ++p) {
      short8 bf = *(const short8*)(smem + rbase + rdoff + p * 1024);
#pragma unroll
      for (int q = 0; q < 4; ++q)
        acc[q] = __builtin_amdgcn_mfma_f32_16x16x32_bf16(wfv[q][p], bf, acc[q], 0, 0, 0);
    }
    // cell (exp2 domain): lane owns j = 128hf+16w+4hi+r, batch col bg+lo
    float hv[4];
#pragma unroll
    for (int r = 0; r < 4; ++r) {
      float iv = rcpa(1.0f + ex2n(acc[0][r]));
      float fv = rcpa(1.0f + ex2n(acc[1][r]));
      float gv = 1.0f - 2.0f * rcpa(ex2(acc[2][r]) + 1.0f);
      float ov = rcpa(1.0f + ex2n(acc[3][r]));
      float cc = fv * c[r] + iv * gv;
      c[r] = cc;
      float th = 1.0f - 2.0f * rcpa(ex2(cc * TWO_L2E) + 1.0f);
      hv[r] = ov * th;
    }
    u32 d0, d1;
    asm("v_cvt_pk_bf16_f32 %0, %1, %2" : "=v"(d0) : "v"(hv[0]), "v"(hv[1]));
    asm("v_cvt_pk_bf16_f32 %0, %1, %2" : "=v"(d1) : "v"(hv[2]), "v"(hv[3]));
    uint2 hw; hw.x = d0; hw.y = d1;
    *(uint2*)(smem + wbbase + wroff_own) = hw;          // own half -> LDS
    u64 v64 = ((u64)d1 << 32) | (u64)d0;                // own half -> exchange
    __hip_atomic_store((u64*)(xb_self[t & 1] + xoff), v64,
                       __ATOMIC_RELAXED, __HIP_MEMORY_SCOPE_AGENT);
    __threadfence();                                     // stores visible agent-wide
    __syncthreads();
    if (tid == 0) {
      __hip_atomic_store(flag_self, (u32)(t + 1),
                         __ATOMIC_RELEASE, __HIP_MEMORY_SCOPE_AGENT);
      while (__hip_atomic_load(flag_par, __ATOMIC_ACQUIRE,
                               __HIP_MEMORY_SCOPE_AGENT) < (u32)(t + 1))
        __builtin_amdgcn_s_sleep(1);
    }
    __syncthreads();
    u64 pv = __hip_atomic_load((u64*)(xb_par[t & 1] + xoff),
                               __ATOMIC_RELAXED, __HIP_MEMORY_SCOPE_AGENT);
    *(u64*)(smem + wbbase + wroff_par) = pv;             // partner half -> LDS
    __syncthreads();                                     // full h_t visible
    if (STORE_H && hf == 0) {
      int4 hv4 = *(const int4*)(smem + wbbase + wboff);
      *(int4*)(h_out + wb_glob + ((size_t)t << 16)) = hv4;
    }
  }

  // ---- persist own-half state (h from final LDS = bf16-rounded) ----
  int fbuf = (T & 1) << 13;
  ushort4 hv4 = *(const ushort4*)(smem + fbuf + wroff_own);
  u16 hb[4] = {hv4.x, hv4.y, hv4.z, hv4.w};
#pragma unroll
  for (int r = 0; r < 4; ++r) {
    int j = 128 * hf + 16 * w + 4 * hi + r;
    h_state[(size_t)(bg + lo) * NH + j] = b2f(hb[r]);
    c_state[(size_t)(bg + lo) * NH + j] = c[r];
  }
}

// ---------------- LayerNorm + projection -----------------------------------
__global__ __launch_bounds__(256) void ln_proj(const float* __restrict__ hn,
                                               const float* __restrict__ lng,
                                               const float* __restrict__ lnb,
                                               const float* __restrict__ pW,
                                               const float* __restrict__ pb,
                                               float* __restrict__ out) {
  __shared__ __align__(16) float nbuf[NH];
  __shared__ float red[8];
  int b = blockIdx.x, tid = threadIdx.x;
  float v = hn[(size_t)b * NH + tid];
  float s = v, s2 = v * v;
#pragma unroll
  for (int o = 32; o > 0; o >>= 1) {
    s  += __shfl_down(s, o);
    s2 += __shfl_down(s2, o);
  }
  if ((tid & 63) == 0) { red[tid >> 6] = s; red[4 + (tid >> 6)] = s2; }
  __syncthreads();
  if (tid == 0) {
    red[0] = red[0] + red[1] + red[2] + red[3];
    red[4] = red[4] + red[5] + red[6] + red[7];
  }
  __syncthreads();
  float mean = red[0] * (1.0f / NH);
  float var  = red[4] * (1.0f / NH) - mean * mean;
  float rs = rsqrtf(var + 1e-5f);
  nbuf[tid] = (v - mean) * rs * lng[tid] + lnb[tid];
  __syncthreads();
  if (tid < NE) {
    float a = pb[tid];
    const float* wr = pW + (size_t)tid * NH;
#pragma unroll 4
    for (int j = 0; j < NH; ++j) a = fmaf(nbuf[j], wr[j], a);
    out[(size_t)b * NE + tid] = a;
  }
}

// ---------------------------------------------------------------------------
extern "C" void kernel_launch(void* const* d_in, const int* in_sizes, int n_in,
                              void* d_out, int out_size, void* d_ws, size_t ws_size,
                              hipStream_t stream) {
  const int*   x     = (const int*)d_in[0];
  const float* emb   = (const float*)d_in[1];
  const float* Wih0  = (const float*)d_in[2];
  const float* Whh0  = (const float*)d_in[3];
  const float* bih0  = (const float*)d_in[4];
  const float* bhh0  = (const float*)d_in[5];
  const float* Wih1  = (const float*)d_in[6];
  const float* Whh1  = (const float*)d_in[7];
  const float* bih1  = (const float*)d_in[8];
  const float* bhh1  = (const float*)d_in[9];
  const float* ln_g  = (const float*)d_in[10];
  const float* ln_b  = (const float*)d_in[11];
  const float* projW = (const float*)d_in[12];
  const float* projb = (const float*)d_in[13];

  hipFuncSetAttribute((const void*)lstm_scan<true>,
                      hipFuncAttributeMaxDynamicSharedMemorySize, XLDS);
  hipFuncSetAttribute((const void*)lstm_scan<false>,
                      hipFuncAttributeMaxDynamicSharedMemorySize, XLDS);

  // pick largest chunk T (divides 512) whose scratch fits ws_size
  const size_t FIXED = 3678208;  // weights+biases+state+xchg+flags
  int T = 512;
  while (T > 4 && FIXED + (size_t)T * 655360 > ws_size) T >>= 1;
  int nch = NS / T;

  char* ws = (char*)d_ws;
  u16*   xp_c  = (u16*)(ws);
  u16*   iobuf = (u16*)(ws + (size_t)T * 524288);   // e chunk / h1 chunk
  char*  wbase = ws + (size_t)T * 655360;
  u16*   wih0b = (u16*)(wbase);
  u16*   whh0b = (u16*)(wbase + 262144);
  u16*   wih1b = (u16*)(wbase + 786432);
  u16*   whh1b = (u16*)(wbase + 1310720);
  float* bc0   = (float*)(wbase + 1835008);
  float* bc1   = (float*)(wbase + 1839104);
  float* h0s   = (float*)(wbase + 1843200);
  float* c0s   = (float*)(wbase + 2105344);
  float* h1s   = (float*)(wbase + 2367488);
  float* c1s   = (float*)(wbase + 2629632);
  char*  xbuf  = wbase + 2891776;                   // 256KB exchange slots
  u32*   flags = (u32*)(wbase + 3153920);           // up to 512KB flag slices

  int nflags = 2 * nch * 512;                       // u32 count (2KB/slice)
  zero_flags<<<(nflags + 255) / 256, 256, 0, stream>>>(flags, nflags);
  prep_weights<<<256, 256, 0, stream>>>(Wih0, Whh0, bih0, bhh0, Wih1, Whh1, bih1, bhh1,
                                        wih0b, whh0b, wih1b, whh1b, bc0, bc1);
  for (int c = 0; c < nch; ++c) {
    int t0 = c * T;
    u32* fl0 = flags + (size_t)(c * 2 + 0) * 512;
    u32* fl1 = flags + (size_t)(c * 2 + 1) * 512;
    embed_chunk<<<T * 32, 256, 0, stream>>>(x, emb, iobuf, t0);
    xp_gemm<NE><<<T * 16, 256, 0, stream>>>(iobuf, wih0b, bc0, xp_c);
    lstm_scan<true><<<32, 512, XLDS, stream>>>(xp_c, whh0b, iobuf, h0s, c0s, T, c == 0,
                                               xbuf, fl0);
    xp_gemm<NH><<<T * 16, 256, 0, stream>>>(iobuf, wih1b, bc1, xp_c);
    lstm_scan<false><<<32, 512, XLDS, stream>>>(xp_c, whh1b, nullptr, h1s, c1s, T, c == 0,
                                                xbuf, fl1);
  }
  ln_proj<<<NB, 256, 0, stream>>>(h1s, ln_g, ln_b, projW, projb, (float*)d_out);
}

// Round 12
// 1677.836 us; speedup vs baseline: 3.7293x; 3.7293x over previous
//
#include <hip/hip_runtime.h>
#include <hip/hip_bf16.h>

// ---------------------------------------------------------------------------
// 2-layer LSTM (B=256,S=512,E=128,H=256) + LayerNorm + projection.
// Round 12: revert R11's per-step cross-WG exchange (XCD L2 non-coherence
// makes per-step fences cost ~us). Instead: LAYER PIPELINING at chunk
// granularity. One 32-WG stage kernel: WGs 0-15 scan L0 chunk s, WGs 16-31
// scan L1 chunk s-1 (independent: L1 chunk s-1 needs only h1(s-1), produced
// at stage s-1 and turned into xp1 by a GEMM between stages). No inter-WG
// sync anywhere. Scan body verbatim round 9 (passed, 517us/chunk-dispatch).
// Stages: nch+1 instead of 2*nch chunk dispatches (T=128 -> 5 vs 8).
// ws: xpA (L0) + xpB (L1) + iobuf (e/h1) + weights/state.
// ---------------------------------------------------------------------------

typedef unsigned short u16;
typedef unsigned int   u32;
using short8 = __attribute__((ext_vector_type(8))) short;
using f32x4  = __attribute__((ext_vector_type(4))) float;

#define NB 256
#define NS 512
#define NE 128
#define NH 256
#define NG 1024  // 4*H

// scan LDS: weights 8 waves * 18 frags * 64 lanes * 16B = 147456, then h dbuf
#define WLDS_FRAGS 18
#define HOFF 147456
#define SCAN_LDS (HOFF + 2 * 16 * NH * 2)   // 163840 = 160 KiB (CU max)

#define L2E     1.4426950408889634f
#define TWO_L2E 2.8853900817779268f

__device__ __forceinline__ u16 f2b(float x) {
  __hip_bfloat16 h = __float2bfloat16(x);
  return __builtin_bit_cast(u16, h);
}
__device__ __forceinline__ float b2f(u16 u) {
  return __builtin_bit_cast(float, (u32)u << 16);
}
__device__ __forceinline__ float ex2(float x)  { return __builtin_amdgcn_exp2f(x); }
__device__ __forceinline__ float ex2n(float x) { return __builtin_amdgcn_exp2f(-x); }
__device__ __forceinline__ float rcpa(float x) { return __builtin_amdgcn_rcpf(x); }

// ---------------- prep: fp32 weights -> bf16 (exp2-prescaled), biases ------
// rows [0,256) i, [256,512) f, [512,768) g, [768,1024) o.
// i,f,o rows scaled by log2e; g rows by 2*log2e (tanh via exp2 of 2x*log2e).
__global__ __launch_bounds__(256) void prep_weights(
    const float* Wih0, const float* Whh0, const float* bih0, const float* bhh0,
    const float* Wih1, const float* Whh1, const float* bih1, const float* bhh1,
    u16* wih0b, u16* whh0b, u16* wih1b, u16* whh1b, float* bc0, float* bc1) {
  int stride = gridDim.x * blockDim.x;
  int tid = blockIdx.x * blockDim.x + threadIdx.x;
  for (int i = tid; i < NG * NE; i += stride) {
    float s = (((i >> 7) >> 8) == 2) ? TWO_L2E : L2E;
    wih0b[i] = f2b(Wih0[i] * s);
  }
  for (int i = tid; i < NG * NH; i += stride) {
    float s = (((i >> 8) >> 8) == 2) ? TWO_L2E : L2E;
    whh0b[i] = f2b(Whh0[i] * s);
    wih1b[i] = f2b(Wih1[i] * s);
    whh1b[i] = f2b(Whh1[i] * s);
  }
  for (int i = tid; i < NG; i += stride) {
    float s = ((i >> 8) == 2) ? TWO_L2E : L2E;
    bc0[i] = (bih0[i] + bhh0[i]) * s;
    bc1[i] = (bih1[i] + bhh1[i]) * s;
  }
}

// ---------------- embedding gather for steps [t0, t0+T) -------------------
__global__ __launch_bounds__(256) void embed_chunk(const int* __restrict__ x,
                                                   const float* __restrict__ emb,
                                                   u16* __restrict__ ebuf, int t0) {
  int gid = blockIdx.x * 256 + threadIdx.x;
  int d4 = gid & 31;
  int sb = gid >> 5;                            // sl*B + b
  int b  = sb & (NB - 1);
  int sl = sb >> 8;
  int tok = x[b * NS + (t0 + sl)];              // x is [B][S]
  float4 v = make_float4(0.f, 0.f, 0.f, 0.f);
  if (tok != 0) v = *(const float4*)(emb + (size_t)tok * NE + d4 * 4);
  ushort4 o;
  o.x = f2b(v.x); o.y = f2b(v.y); o.z = f2b(v.z); o.w = f2b(v.w);
  *(ushort4*)(ebuf + (size_t)sb * NE + d4 * 4) = o;
}

// ---------------- xp GEMM: writes scan-fragment layout ---------------------
//   e = (((t*16+bgrp)*8+ws)*8+mts)*256 + (his*16+lo)*4 + rs
template <int K>
__global__ __launch_bounds__(256) void xp_gemm(const u16* __restrict__ A,
                                               const u16* __restrict__ W,
                                               const float* __restrict__ bias,
                                               u16* __restrict__ Cout) {
  __shared__ __align__(16) char lds[2 * 128 * 80];
  char* Asm = lds;
  char* Bsm = lds + 128 * 80;
  int tid = threadIdx.x;
  int w = tid >> 6, l = tid & 63;
  int hi = l >> 4, lo = l & 15;
  int mblk = blockIdx.x >> 3, nblk = blockIdx.x & 7;
  size_t arow0 = (size_t)mblk * 128;
  int g0 = nblk * 128;
  int wm = (w >> 1) * 64, wn = (w & 1) * 64;
  f32x4 acc[4][4] = {};
  int r = tid >> 1, cp = tid & 1;

  for (int k0 = 0; k0 < K; k0 += 32) {
    int4 a0 = *(const int4*)(A + (arow0 + r) * K + k0 + cp * 16);
    int4 a1 = *(const int4*)(A + (arow0 + r) * K + k0 + cp * 16 + 8);
    int4 b0 = *(const int4*)(W + (size_t)(g0 + r) * K + k0 + cp * 16);
    int4 b1 = *(const int4*)(W + (size_t)(g0 + r) * K + k0 + cp * 16 + 8);
    *(int4*)(Asm + r * 80 + cp * 32)      = a0;
    *(int4*)(Asm + r * 80 + cp * 32 + 16) = a1;
    *(int4*)(Bsm + r * 80 + cp * 32)      = b0;
    *(int4*)(Bsm + r * 80 + cp * 32 + 16) = b1;
    __syncthreads();
    short8 af[4], bfr[4];
#pragma unroll
    for (int mt = 0; mt < 4; ++mt)
      af[mt] = *(const short8*)(Asm + (wm + mt * 16 + lo) * 80 + hi * 16);
#pragma unroll
    for (int nt = 0; nt < 4; ++nt)
      bfr[nt] = *(const short8*)(Bsm + (wn + nt * 16 + lo) * 80 + hi * 16);
#pragma unroll
    for (int mt = 0; mt < 4; ++mt)
#pragma unroll
      for (int nt = 0; nt < 4; ++nt)
        acc[mt][nt] = __builtin_amdgcn_mfma_f32_16x16x32_bf16(af[mt], bfr[nt], acc[mt][nt], 0, 0, 0);
    __syncthreads();
  }
  // epilogue: D lane mapping col = lane&15 (gc), row = (lane>>4)*4 + reg
#pragma unroll
  for (int nt = 0; nt < 4; ++nt) {
    int gc = g0 + wn + nt * 16 + lo;
    float bv = bias[gc];
    int ws_ = (gc >> 4) & 7, mts = gc >> 7, his = (gc >> 2) & 3, rs = gc & 3;
    size_t gbase = ((size_t)(ws_ * 8 + mts) << 8) + (size_t)(his * 16) * 4 + rs;
#pragma unroll
    for (int mt = 0; mt < 4; ++mt) {
      size_t row = arow0 + wm + mt * 16 + hi * 4;
#pragma unroll
      for (int rr = 0; rr < 4; ++rr) {
        size_t rw = row + rr;
        int t = (int)(rw >> 8), ba = (int)(rw & 255);
        size_t e = ((size_t)(t * 16 + (ba >> 4)) << 14) + gbase + (size_t)(ba & 15) * 4;
        Cout[e] = f2b(acc[mt][nt][rr] + bv);
      }
    }
  }
}

// ---------------- LSTM scan stage: L0 chunk s + L1 chunk s-1 ---------------
// 32 WGs x 512 thr. WGs 0-15: role A (layer 0, batch group bid); WGs 16-31:
// role B (layer 1, batch group bid-16). Roles touch disjoint buffers; no
// inter-WG communication. Body = round-9 scan (passed) with runtime role
// pointer selection; inactive roles exit immediately.
__global__ __launch_bounds__(512, 2)
void scan_stage(const u16* __restrict__ xpA, const u16* __restrict__ whhA,
                u16* __restrict__ houtA, float* __restrict__ hsA,
                float* __restrict__ csA, int firstA, int activeA,
                const u16* __restrict__ xpB, const u16* __restrict__ whhB,
                float* __restrict__ hsB, float* __restrict__ csB,
                int firstB, int activeB, int T) {
  extern __shared__ __align__(16) char smem[];
  int bid = blockIdx.x;
  int roleB = bid >> 4;
  if (roleB ? !activeB : !activeA) return;
  const u16* xp      = roleB ? xpB  : xpA;
  const u16* whh     = roleB ? whhB : whhA;
  u16*       hout    = roleB ? (u16*)0 : houtA;
  float*     h_state = roleB ? hsB : hsA;
  float*     c_state = roleB ? csB : csA;
  int        first   = roleB ? firstB : firstA;
  int bgi = bid & 15;
  int bg = bgi * 16;

  int tid = threadIdx.x;
  int w = tid >> 6, l = tid & 63;
  int hi = l >> 4, lo = l & 15;

  // ---- load Whh into regs + LDS (once) ----
  int wbase = w * (WLDS_FRAGS * 1024) + l * 16;   // per-lane 16B slots
  short8 wfv[8][5];   // p = 3..7
  short8 wfv2[6];     // p == 2, mt = 2..7
#pragma unroll
  for (int mt = 0; mt < 8; ++mt) {
#pragma unroll
    for (int p = 0; p < 8; ++p) {
      const u16* src = whh + (size_t)(16 * (w + 8 * mt) + lo) * NH + p * 32 + hi * 8;
      short8 v = *(const short8*)src;
      if (p < 2)                 *(short8*)(smem + wbase + (p * 8 + mt) * 1024) = v;
      else if (p == 2 && mt < 2) *(short8*)(smem + wbase + (16 + mt) * 1024) = v;
      else if (p == 2)           wfv2[mt - 2] = v;
      else                       wfv[mt][p - 3] = v;
    }
  }

  // ---- init h (LDS buffer 0, frag-major) and c (regs) ----
  float c[2][4];
  if (first) {
    for (int i = tid; i < 16 * NH / 2; i += 512) ((u32*)(smem + HOFF))[i] = 0;
#pragma unroll
    for (int g = 0; g < 2; ++g)
#pragma unroll
      for (int r = 0; r < 4; ++r) c[g][r] = 0.0f;
  } else {
    for (int i = tid; i < 16 * NH; i += 512) {
      int b = i >> 8, k = i & 255;
      int p = k >> 5, hp = (k >> 3) & 3, kp = k & 7;
      int xx = hp * 16 + b;
      u16 hb = f2b(h_state[(size_t)(bg + b) * NH + k]);
      *(u16*)(smem + HOFF + p * 1024 + (xx ^ ((xx >> 3) & 7)) * 16 + kp * 2) = hb;
    }
#pragma unroll
    for (int g = 0; g < 2; ++g)
#pragma unroll
      for (int r = 0; r < 4; ++r) {
        int j = 16 * w + 128 * g + hi * 4 + r;
        c[g][r] = c_state[(size_t)(bg + lo) * NH + j];
      }
  }
  __syncthreads();

  // ---- step-invariant offsets (relative to h buffer base) ----
  int rdoff = (l ^ ((l >> 3) & 7)) * 16;            // bfrag read offset
  int wroff[2];                                      // h write offsets (g=0,1)
#pragma unroll
  for (int g = 0; g < 2; ++g) {
    int xx = (2 * (w & 1) + (hi >> 1)) * 16 + lo;   // h'_j*16 + b
    wroff[g] = (4 * g + (w >> 1)) * 1024 + (xx ^ ((xx >> 3) & 7)) * 16 + 8 * (hi & 1);
  }
  // h_out writeback: thread -> (batch bq, k-chunk kc): logical chunk kc
  int bq = tid >> 5, kc = tid & 31;
  int xw = (kc & 3) * 16 + bq;
  int wboff = (kc >> 2) * 1024 + (xw ^ ((xw >> 3) & 7)) * 16;
  size_t wb_glob = (size_t)(bg + bq) * NH + kc * 8;

  // xp fragment-layout pointer: wave slice, per-lane 4 elements (8B)
  const u16* xpp = xp + ((size_t)(bgi * 8 + w) * 2048) + (size_t)l * 4;

  // ---- prefetch xp for t=0 ----
  ushort4 xq[8];
#pragma unroll
  for (int mt = 0; mt < 8; ++mt) xq[mt] = *(const ushort4*)(xpp + mt * 256);

  f32x4 acc[8];
  for (int t = 0; t < T; ++t) {
    int rbase = HOFF + ((t & 1) << 13);       // read buffer (h_{t-1})
    int wbbase = HOFF + ((~t & 1) << 13);     // write buffer (h_t)
    // acc init from prefetched xp (bias folded in by GEMM)
#pragma unroll
    for (int mt = 0; mt < 8; ++mt) {
      f32x4 a;
      a[0] = b2f(xq[mt].x); a[1] = b2f(xq[mt].y);
      a[2] = b2f(xq[mt].z); a[3] = b2f(xq[mt].w);
      acc[mt] = a;
    }
    // prefetch next step's xp (t=T-1 overruns into the next ws buffer: safe)
    xpp += 262144;
#pragma unroll
    for (int mt = 0; mt < 8; ++mt) xq[mt] = *(const ushort4*)(xpp + mt * 256);
    // GEMV: 8 k-slots x 8 m-tiles; bfrag at rbase + rdoff + p*1024
#pragma unroll
    for (int p = 0; p < 8; ++p) {
      short8 bf = *(const short8*)(smem + rbase + rdoff + p * 1024);
#pragma unroll
      for (int mt = 0; mt < 8; ++mt) {
        short8 af;
        if (p < 2)                 af = *(const short8*)(smem + wbase + (p * 8 + mt) * 1024);
        else if (p == 2 && mt < 2) af = *(const short8*)(smem + wbase + (16 + mt) * 1024);
        else if (p == 2)           af = wfv2[mt - 2];
        else                       af = wfv[mt][p - 3];
        acc[mt] = __builtin_amdgcn_mfma_f32_16x16x32_bf16(af, bf, acc[mt], 0, 0, 0);
      }
    }
    // cell update (exp2 domain): lane owns gate rows j = 16w+128g+4hi+r
#pragma unroll
    for (int g = 0; g < 2; ++g) {
      float hv[4];
#pragma unroll
      for (int r = 0; r < 4; ++r) {
        float iv = rcpa(1.0f + ex2n(acc[g][r]));
        float fv = rcpa(1.0f + ex2n(acc[2 + g][r]));
        float gv = 1.0f - 2.0f * rcpa(ex2(acc[4 + g][r]) + 1.0f);
        float ov = rcpa(1.0f + ex2n(acc[6 + g][r]));
        float cc = fv * c[g][r] + iv * gv;
        c[g][r] = cc;
        float th = 1.0f - 2.0f * rcpa(ex2(cc * TWO_L2E) + 1.0f);
        hv[r] = ov * th;
      }
      u32 d0, d1;
      asm("v_cvt_pk_bf16_f32 %0, %1, %2" : "=v"(d0) : "v"(hv[0]), "v"(hv[1]));
      asm("v_cvt_pk_bf16_f32 %0, %1, %2" : "=v"(d1) : "v"(hv[2]), "v"(hv[3]));
      uint2 hw; hw.x = d0; hw.y = d1;
      *(uint2*)(smem + wbbase + wroff[g]) = hw;   // ds_write_b64, conflict-free
    }
    __syncthreads();  // h_t visible; ONLY barrier in the step
    if (hout) {
      int4 hv4 = *(const int4*)(smem + wbbase + wboff);     // logical chunk kc
      *(int4*)(hout + wb_glob + ((size_t)t << 16)) = hv4;   // global chunk kc
    }
  }

  // ---- persist state (once; h from final LDS buffer = bf16-rounded) ----
  int fbuf = HOFF + ((T & 1) << 13);
#pragma unroll
  for (int g = 0; g < 2; ++g) {
    ushort4 hv4 = *(const ushort4*)(smem + fbuf + wroff[g]);
    int j = 16 * w + 128 * g + 4 * hi;
    u16 hb[4] = {hv4.x, hv4.y, hv4.z, hv4.w};
#pragma unroll
    for (int r = 0; r < 4; ++r) {
      h_state[(size_t)(bg + lo) * NH + j + r] = b2f(hb[r]);
      c_state[(size_t)(bg + lo) * NH + j + r] = c[g][r];
    }
  }
}

// ---------------- LayerNorm + projection -----------------------------------
__global__ __launch_bounds__(256) void ln_proj(const float* __restrict__ hn,
                                               const float* __restrict__ lng,
                                               const float* __restrict__ lnb,
                                               const float* __restrict__ pW,
                                               const float* __restrict__ pb,
                                               float* __restrict__ out) {
  __shared__ __align__(16) float nbuf[NH];
  __shared__ float red[8];
  int b = blockIdx.x, tid = threadIdx.x;
  float v = hn[(size_t)b * NH + tid];
  float s = v, s2 = v * v;
#pragma unroll
  for (int o = 32; o > 0; o >>= 1) {
    s  += __shfl_down(s, o);
    s2 += __shfl_down(s2, o);
  }
  if ((tid & 63) == 0) { red[tid >> 6] = s; red[4 + (tid >> 6)] = s2; }
  __syncthreads();
  if (tid == 0) {
    red[0] = red[0] + red[1] + red[2] + red[3];
    red[4] = red[4] + red[5] + red[6] + red[7];
  }
  __syncthreads();
  float mean = red[0] * (1.0f / NH);
  float var  = red[4] * (1.0f / NH) - mean * mean;
  float rs = rsqrtf(var + 1e-5f);
  nbuf[tid] = (v - mean) * rs * lng[tid] + lnb[tid];
  __syncthreads();
  if (tid < NE) {
    float a = pb[tid];
    const float* wr = pW + (size_t)tid * NH;
#pragma unroll 4
    for (int j = 0; j < NH; ++j) a = fmaf(nbuf[j], wr[j], a);
    out[(size_t)b * NE + tid] = a;
  }
}

// ---------------------------------------------------------------------------
extern "C" void kernel_launch(void* const* d_in, const int* in_sizes, int n_in,
                              void* d_out, int out_size, void* d_ws, size_t ws_size,
                              hipStream_t stream) {
  const int*   x     = (const int*)d_in[0];
  const float* emb   = (const float*)d_in[1];
  const float* Wih0  = (const float*)d_in[2];
  const float* Whh0  = (const float*)d_in[3];
  const float* bih0  = (const float*)d_in[4];
  const float* bhh0  = (const float*)d_in[5];
  const float* Wih1  = (const float*)d_in[6];
  const float* Whh1  = (const float*)d_in[7];
  const float* bih1  = (const float*)d_in[8];
  const float* bhh1  = (const float*)d_in[9];
  const float* ln_g  = (const float*)d_in[10];
  const float* ln_b  = (const float*)d_in[11];
  const float* projW = (const float*)d_in[12];
  const float* projb = (const float*)d_in[13];

  hipFuncSetAttribute((const void*)scan_stage,
                      hipFuncAttributeMaxDynamicSharedMemorySize, SCAN_LDS);

  // pick largest chunk T <= 128 (divides 512) whose scratch fits ws_size
  // per-T bytes: xpA + xpB (T*524288 each) + iobuf (T*131072) = T*1179648
  const size_t FIXED = 2891776;
  int T = 128;
  while (T > 4 && FIXED + (size_t)T * 1179648 > ws_size) T >>= 1;
  int nch = NS / T;

  char* ws = (char*)d_ws;
  u16*   xpA   = (u16*)(ws);
  u16*   xpB   = (u16*)(ws + (size_t)T * 524288);
  u16*   iobuf = (u16*)(ws + (size_t)T * 1048576);  // e chunk / h1 chunk
  char*  wbase = ws + (size_t)T * 1179648;
  u16*   wih0b = (u16*)(wbase);
  u16*   whh0b = (u16*)(wbase + 262144);
  u16*   wih1b = (u16*)(wbase + 786432);
  u16*   whh1b = (u16*)(wbase + 1310720);
  float* bc0   = (float*)(wbase + 1835008);
  float* bc1   = (float*)(wbase + 1839104);
  float* hs0   = (float*)(wbase + 1843200);
  float* cs0   = (float*)(wbase + 2105344);
  float* hs1   = (float*)(wbase + 2367488);
  float* cs1   = (float*)(wbase + 2629632);

  prep_weights<<<256, 256, 0, stream>>>(Wih0, Whh0, bih0, bhh0, Wih1, Whh1, bih1, bhh1,
                                        wih0b, whh0b, wih1b, whh1b, bc0, bc1);
  // prologue: xpA for L0 chunk 0
  embed_chunk<<<T * 32, 256, 0, stream>>>(x, emb, iobuf, 0);
  xp_gemm<NE><<<T * 16, 256, 0, stream>>>(iobuf, wih0b, bc0, xpA);

  for (int s = 0; s <= nch; ++s) {
    int aA = (s < nch) ? 1 : 0;
    int aB = (s >= 1) ? 1 : 0;
    // stage s: L0 chunk s (writes h1(s) -> iobuf) || L1 chunk s-1 (reads xpB)
    scan_stage<<<32, 512, SCAN_LDS, stream>>>(
        xpA, whh0b, iobuf, hs0, cs0, (s == 0) ? 1 : 0, aA,
        xpB, whh1b, hs1, cs1, (s == 1) ? 1 : 0, aB, T);
    if (s < nch) {
      // h1(s) -> xpB for L1 chunk s (consumed at stage s+1)
      xp_gemm<NH><<<T * 16, 256, 0, stream>>>(iobuf, wih1b, bc1, xpB);
      if (s + 1 < nch) {
        // e(s+1) -> xpA for L0 chunk s+1 (iobuf free: gemmB already read it)
        embed_chunk<<<T * 32, 256, 0, stream>>>(x, emb, iobuf, (s + 1) * T);
        xp_gemm<NE><<<T * 16, 256, 0, stream>>>(iobuf, wih0b, bc0, xpA);
      }
    }
  }
  ln_proj<<<NB, 256, 0, stream>>>(hs1, ln_g, ln_b, projW, projb, (float*)d_out);
}

// Round 13
// 1652.657 us; speedup vs baseline: 3.7861x; 1.0152x over previous
//
#include <hip/hip_runtime.h>
#include <hip/hip_bf16.h>

// ---------------------------------------------------------------------------
// 2-layer LSTM (B=256,S=512,E=128,H=256) + LayerNorm + projection.
// Round 13: kill the serial inter-stage glue. Stage kernel now has THREE
// roles: A (WG 0-15)  = L0 scan chunk s          (verbatim R12 scan body)
//        B (WG 16-31) = L1 scan chunk s-1        (verbatim R12 scan body)
//        C (WG 32-63) = fused embed+gemmA producing xpA for chunk s+1
//                       (depends only on x/emb/Wih0 -> runs under the stage
//                        on idle CUs; 2 tile-teams of 256 thr per WG).
// Only gemmB (h1(s) -> xpB(s)) remains serial between stages. T=64 shortens
// the pipeline critical path (576 step-slots) and guarantees ws fit.
// xpA is double-buffered: chunk c lives in xpA[c&1].
// ---------------------------------------------------------------------------

typedef unsigned short u16;
typedef unsigned int   u32;
using short8 = __attribute__((ext_vector_type(8))) short;
using f32x4  = __attribute__((ext_vector_type(4))) float;

#define NB 256
#define NS 512
#define NE 128
#define NH 256
#define NG 1024  // 4*H

// scan LDS: weights 8 waves * 18 frags * 64 lanes * 16B = 147456, then h dbuf
#define WLDS_FRAGS 18
#define HOFF 147456
#define SCAN_LDS (HOFF + 2 * 16 * NH * 2)   // 163840 = 160 KiB (CU max)

#define L2E     1.4426950408889634f
#define TWO_L2E 2.8853900817779268f

__device__ __forceinline__ u16 f2b(float x) {
  __hip_bfloat16 h = __float2bfloat16(x);
  return __builtin_bit_cast(u16, h);
}
__device__ __forceinline__ float b2f(u16 u) {
  return __builtin_bit_cast(float, (u32)u << 16);
}
__device__ __forceinline__ float ex2(float x)  { return __builtin_amdgcn_exp2f(x); }
__device__ __forceinline__ float ex2n(float x) { return __builtin_amdgcn_exp2f(-x); }
__device__ __forceinline__ float rcpa(float x) { return __builtin_amdgcn_rcpf(x); }

// ---------------- prep: fp32 weights -> bf16 (exp2-prescaled), biases ------
__global__ __launch_bounds__(256) void prep_weights(
    const float* Wih0, const float* Whh0, const float* bih0, const float* bhh0,
    const float* Wih1, const float* Whh1, const float* bih1, const float* bhh1,
    u16* wih0b, u16* whh0b, u16* wih1b, u16* whh1b, float* bc0, float* bc1) {
  int stride = gridDim.x * blockDim.x;
  int tid = blockIdx.x * blockDim.x + threadIdx.x;
  for (int i = tid; i < NG * NE; i += stride) {
    float s = (((i >> 7) >> 8) == 2) ? TWO_L2E : L2E;
    wih0b[i] = f2b(Wih0[i] * s);
  }
  for (int i = tid; i < NG * NH; i += stride) {
    float s = (((i >> 8) >> 8) == 2) ? TWO_L2E : L2E;
    whh0b[i] = f2b(Whh0[i] * s);
    wih1b[i] = f2b(Wih1[i] * s);
    whh1b[i] = f2b(Whh1[i] * s);
  }
  for (int i = tid; i < NG; i += stride) {
    float s = ((i >> 8) == 2) ? TWO_L2E : L2E;
    bc0[i] = (bih0[i] + bhh0[i]) * s;
    bc1[i] = (bih1[i] + bhh1[i]) * s;
  }
}

// ---------------- embedding gather for steps [t0, t0+T) (prologue only) ----
__global__ __launch_bounds__(256) void embed_chunk(const int* __restrict__ x,
                                                   const float* __restrict__ emb,
                                                   u16* __restrict__ ebuf, int t0) {
  int gid = blockIdx.x * 256 + threadIdx.x;
  int d4 = gid & 31;
  int sb = gid >> 5;                            // sl*B + b
  int b  = sb & (NB - 1);
  int sl = sb >> 8;
  int tok = x[b * NS + (t0 + sl)];              // x is [B][S]
  float4 v = make_float4(0.f, 0.f, 0.f, 0.f);
  if (tok != 0) v = *(const float4*)(emb + (size_t)tok * NE + d4 * 4);
  ushort4 o;
  o.x = f2b(v.x); o.y = f2b(v.y); o.z = f2b(v.z); o.w = f2b(v.w);
  *(ushort4*)(ebuf + (size_t)sb * NE + d4 * 4) = o;
}

// ---------------- xp GEMM: writes scan-fragment layout ---------------------
//   e = (((t*16+bgrp)*8+ws)*8+mts)*256 + (his*16+lo)*4 + rs
template <int K>
__global__ __launch_bounds__(256) void xp_gemm(const u16* __restrict__ A,
                                               const u16* __restrict__ W,
                                               const float* __restrict__ bias,
                                               u16* __restrict__ Cout) {
  __shared__ __align__(16) char lds[2 * 128 * 80];
  char* Asm = lds;
  char* Bsm = lds + 128 * 80;
  int tid = threadIdx.x;
  int w = tid >> 6, l = tid & 63;
  int hi = l >> 4, lo = l & 15;
  int mblk = blockIdx.x >> 3, nblk = blockIdx.x & 7;
  size_t arow0 = (size_t)mblk * 128;
  int g0 = nblk * 128;
  int wm = (w >> 1) * 64, wn = (w & 1) * 64;
  f32x4 acc[4][4] = {};
  int r = tid >> 1, cp = tid & 1;

  for (int k0 = 0; k0 < K; k0 += 32) {
    int4 a0 = *(const int4*)(A + (arow0 + r) * K + k0 + cp * 16);
    int4 a1 = *(const int4*)(A + (arow0 + r) * K + k0 + cp * 16 + 8);
    int4 b0 = *(const int4*)(W + (size_t)(g0 + r) * K + k0 + cp * 16);
    int4 b1 = *(const int4*)(W + (size_t)(g0 + r) * K + k0 + cp * 16 + 8);
    *(int4*)(Asm + r * 80 + cp * 32)      = a0;
    *(int4*)(Asm + r * 80 + cp * 32 + 16) = a1;
    *(int4*)(Bsm + r * 80 + cp * 32)      = b0;
    *(int4*)(Bsm + r * 80 + cp * 32 + 16) = b1;
    __syncthreads();
    short8 af[4], bfr[4];
#pragma unroll
    for (int mt = 0; mt < 4; ++mt)
      af[mt] = *(const short8*)(Asm + (wm + mt * 16 + lo) * 80 + hi * 16);
#pragma unroll
    for (int nt = 0; nt < 4; ++nt)
      bfr[nt] = *(const short8*)(Bsm + (wn + nt * 16 + lo) * 80 + hi * 16);
#pragma unroll
    for (int mt = 0; mt < 4; ++mt)
#pragma unroll
      for (int nt = 0; nt < 4; ++nt)
        acc[mt][nt] = __builtin_amdgcn_mfma_f32_16x16x32_bf16(af[mt], bfr[nt], acc[mt][nt], 0, 0, 0);
    __syncthreads();
  }
#pragma unroll
  for (int nt = 0; nt < 4; ++nt) {
    int gc = g0 + wn + nt * 16 + lo;
    float bv = bias[gc];
    int ws_ = (gc >> 4) & 7, mts = gc >> 7, his = (gc >> 2) & 3, rs = gc & 3;
    size_t gbase = ((size_t)(ws_ * 8 + mts) << 8) + (size_t)(his * 16) * 4 + rs;
#pragma unroll
    for (int mt = 0; mt < 4; ++mt) {
      size_t row = arow0 + wm + mt * 16 + hi * 4;
#pragma unroll
      for (int rr = 0; rr < 4; ++rr) {
        size_t rw = row + rr;
        int t = (int)(rw >> 8), ba = (int)(rw & 255);
        size_t e = ((size_t)(t * 16 + (ba >> 4)) << 14) + gbase + (size_t)(ba & 15) * 4;
        Cout[e] = f2b(acc[mt][nt][rr] + bv);
      }
    }
  }
}

// ---------------- stage: roles A/B (scan) + C (fused embed+gemmA) ----------
__global__ __launch_bounds__(512, 2)
void scan_stage(const u16* __restrict__ xpA, const u16* __restrict__ whhA,
                u16* __restrict__ houtA, float* __restrict__ hsA,
                float* __restrict__ csA, int firstA, int activeA,
                const u16* __restrict__ xpB, const u16* __restrict__ whhB,
                float* __restrict__ hsB, float* __restrict__ csB,
                int firstB, int activeB,
                const int* __restrict__ x, const float* __restrict__ emb,
                const u16* __restrict__ wih0b, const float* __restrict__ bc0,
                u16* __restrict__ xpC, int t0c, int activeC, int T) {
  extern __shared__ __align__(16) char smem[];
  int bid = blockIdx.x;
  int tid = threadIdx.x;

  if (bid >= 32) {
    // ---------------- role C: fused embed + gemmA for chunk s+1 -----------
    if (!activeC) return;
    int team = tid >> 8, tt = tid & 255;
    char* Asm = smem + team * 40960;
    char* Bsm = Asm + 20480;
    int wq = tt >> 6, lq = tt & 63;
    int hiq = lq >> 4, loq = lq & 15;
    int wm = (wq >> 1) * 64, wn = (wq & 1) * 64;
    int r = tt >> 1, cp = tt & 1;
    int njobs = T * 16;                       // (T*2 mblks) x 8 nblks
    for (int j = (bid - 32) * 2 + team; j < njobs; j += 64) {
      int mblk = j >> 3, nblk = j & 7;
      size_t arow0 = (size_t)mblk * 128;
      int g0 = nblk * 128;
      f32x4 acc[4][4] = {};
      // gather source for staging row r: e[row][k] = emb[tok][k]
      int rw = (int)(arow0 + r);
      int sl = rw >> 8, ba = rw & 255;
      int tok = x[ba * NS + t0c + sl];
      const float* erow = emb + (size_t)tok * NE;
      for (int k0 = 0; k0 < NE; k0 += 32) {
        const float* src = erow + k0 + cp * 16;
        u32 pk[8];
#pragma unroll
        for (int q = 0; q < 8; ++q) {
          float a = src[2 * q], b = src[2 * q + 1];
          if (tok == 0) { a = 0.0f; b = 0.0f; }
          pk[q] = (u32)f2b(a) | ((u32)f2b(b) << 16);
        }
        *(int4*)(Asm + r * 80 + cp * 32)      = *(int4*)&pk[0];
        *(int4*)(Asm + r * 80 + cp * 32 + 16) = *(int4*)&pk[4];
        int4 b0 = *(const int4*)(wih0b + (size_t)(g0 + r) * NE + k0 + cp * 16);
        int4 b1 = *(const int4*)(wih0b + (size_t)(g0 + r) * NE + k0 + cp * 16 + 8);
        *(int4*)(Bsm + r * 80 + cp * 32)      = b0;
        *(int4*)(Bsm + r * 80 + cp * 32 + 16) = b1;
        __syncthreads();
        short8 af[4], bfr[4];
#pragma unroll
        for (int mt = 0; mt < 4; ++mt)
          af[mt] = *(const short8*)(Asm + (wm + mt * 16 + loq) * 80 + hiq * 16);
#pragma unroll
        for (int nt = 0; nt < 4; ++nt)
          bfr[nt] = *(const short8*)(Bsm + (wn + nt * 16 + loq) * 80 + hiq * 16);
#pragma unroll
        for (int mt = 0; mt < 4; ++mt)
#pragma unroll
          for (int nt = 0; nt < 4; ++nt)
            acc[mt][nt] = __builtin_amdgcn_mfma_f32_16x16x32_bf16(af[mt], bfr[nt], acc[mt][nt], 0, 0, 0);
        __syncthreads();
      }
#pragma unroll
      for (int nt = 0; nt < 4; ++nt) {
        int gc = g0 + wn + nt * 16 + loq;
        float bv = bc0[gc];
        int ws_ = (gc >> 4) & 7, mts = gc >> 7, his = (gc >> 2) & 3, rs = gc & 3;
        size_t gbase = ((size_t)(ws_ * 8 + mts) << 8) + (size_t)(his * 16) * 4 + rs;
#pragma unroll
        for (int mt = 0; mt < 4; ++mt) {
          size_t row = arow0 + wm + mt * 16 + hiq * 4;
#pragma unroll
          for (int rr = 0; rr < 4; ++rr) {
            size_t rw2 = row + rr;
            int t = (int)(rw2 >> 8), ba2 = (int)(rw2 & 255);
            size_t e = ((size_t)(t * 16 + (ba2 >> 4)) << 14) + gbase + (size_t)(ba2 & 15) * 4;
            xpC[e] = f2b(acc[mt][nt][rr] + bv);
          }
        }
      }
    }
    return;
  }

  // ---------------- roles A/B: scan (verbatim R12 body) --------------------
  int roleB = bid >> 4;
  if (roleB ? !activeB : !activeA) return;
  const u16* xp      = roleB ? xpB  : xpA;
  const u16* whh     = roleB ? whhB : whhA;
  u16*       hout    = roleB ? (u16*)0 : houtA;
  float*     h_state = roleB ? hsB : hsA;
  float*     c_state = roleB ? csB : csA;
  int        first   = roleB ? firstB : firstA;
  int bgi = bid & 15;
  int bg = bgi * 16;

  int w = tid >> 6, l = tid & 63;
  int hi = l >> 4, lo = l & 15;

  // ---- load Whh into regs + LDS (once) ----
  int wbase = w * (WLDS_FRAGS * 1024) + l * 16;
  short8 wfv[8][5];   // p = 3..7
  short8 wfv2[6];     // p == 2, mt = 2..7
#pragma unroll
  for (int mt = 0; mt < 8; ++mt) {
#pragma unroll
    for (int p = 0; p < 8; ++p) {
      const u16* src = whh + (size_t)(16 * (w + 8 * mt) + lo) * NH + p * 32 + hi * 8;
      short8 v = *(const short8*)src;
      if (p < 2)                 *(short8*)(smem + wbase + (p * 8 + mt) * 1024) = v;
      else if (p == 2 && mt < 2) *(short8*)(smem + wbase + (16 + mt) * 1024) = v;
      else if (p == 2)           wfv2[mt - 2] = v;
      else                       wfv[mt][p - 3] = v;
    }
  }

  // ---- init h (LDS buffer 0, frag-major) and c (regs) ----
  float c[2][4];
  if (first) {
    for (int i = tid; i < 16 * NH / 2; i += 512) ((u32*)(smem + HOFF))[i] = 0;
#pragma unroll
    for (int g = 0; g < 2; ++g)
#pragma unroll
      for (int r = 0; r < 4; ++r) c[g][r] = 0.0f;
  } else {
    for (int i = tid; i < 16 * NH; i += 512) {
      int b = i >> 8, k = i & 255;
      int p = k >> 5, hp = (k >> 3) & 3, kp = k & 7;
      int xx = hp * 16 + b;
      u16 hb = f2b(h_state[(size_t)(bg + b) * NH + k]);
      *(u16*)(smem + HOFF + p * 1024 + (xx ^ ((xx >> 3) & 7)) * 16 + kp * 2) = hb;
    }
#pragma unroll
    for (int g = 0; g < 2; ++g)
#pragma unroll
      for (int r = 0; r < 4; ++r) {
        int j = 16 * w + 128 * g + hi * 4 + r;
        c[g][r] = c_state[(size_t)(bg + lo) * NH + j];
      }
  }
  __syncthreads();

  // ---- step-invariant offsets ----
  int rdoff = (l ^ ((l >> 3) & 7)) * 16;
  int wroff[2];
#pragma unroll
  for (int g = 0; g < 2; ++g) {
    int xx = (2 * (w & 1) + (hi >> 1)) * 16 + lo;
    wroff[g] = (4 * g + (w >> 1)) * 1024 + (xx ^ ((xx >> 3) & 7)) * 16 + 8 * (hi & 1);
  }
  int bq = tid >> 5, kc = tid & 31;
  int xw = (kc & 3) * 16 + bq;
  int wboff = (kc >> 2) * 1024 + (xw ^ ((xw >> 3) & 7)) * 16;
  size_t wb_glob = (size_t)(bg + bq) * NH + kc * 8;

  const u16* xpp = xp + ((size_t)(bgi * 8 + w) * 2048) + (size_t)l * 4;

  ushort4 xq[8];
#pragma unroll
  for (int mt = 0; mt < 8; ++mt) xq[mt] = *(const ushort4*)(xpp + mt * 256);

  f32x4 acc[8];
  for (int t = 0; t < T; ++t) {
    int rbase = HOFF + ((t & 1) << 13);
    int wbbase = HOFF + ((~t & 1) << 13);
#pragma unroll
    for (int mt = 0; mt < 8; ++mt) {
      f32x4 a;
      a[0] = b2f(xq[mt].x); a[1] = b2f(xq[mt].y);
      a[2] = b2f(xq[mt].z); a[3] = b2f(xq[mt].w);
      acc[mt] = a;
    }
    xpp += 262144;   // next t (final overrun lands in adjacent ws buffer: discarded)
#pragma unroll
    for (int mt = 0; mt < 8; ++mt) xq[mt] = *(const ushort4*)(xpp + mt * 256);
#pragma unroll
    for (int p = 0; p < 8; ++p) {
      short8 bf = *(const short8*)(smem + rbase + rdoff + p * 1024);
#pragma unroll
      for (int mt = 0; mt < 8; ++mt) {
        short8 af;
        if (p < 2)                 af = *(const short8*)(smem + wbase + (p * 8 + mt) * 1024);
        else if (p == 2 && mt < 2) af = *(const short8*)(smem + wbase + (16 + mt) * 1024);
        else if (p == 2)           af = wfv2[mt - 2];
        else                       af = wfv[mt][p - 3];
        acc[mt] = __builtin_amdgcn_mfma_f32_16x16x32_bf16(af, bf, acc[mt], 0, 0, 0);
      }
    }
#pragma unroll
    for (int g = 0; g < 2; ++g) {
      float hv[4];
#pragma unroll
      for (int r = 0; r < 4; ++r) {
        float iv = rcpa(1.0f + ex2n(acc[g][r]));
        float fv = rcpa(1.0f + ex2n(acc[2 + g][r]));
        float gv = 1.0f - 2.0f * rcpa(ex2(acc[4 + g][r]) + 1.0f);
        float ov = rcpa(1.0f + ex2n(acc[6 + g][r]));
        float cc = fv * c[g][r] + iv * gv;
        c[g][r] = cc;
        float th = 1.0f - 2.0f * rcpa(ex2(cc * TWO_L2E) + 1.0f);
        hv[r] = ov * th;
      }
      u32 d0, d1;
      asm("v_cvt_pk_bf16_f32 %0, %1, %2" : "=v"(d0) : "v"(hv[0]), "v"(hv[1]));
      asm("v_cvt_pk_bf16_f32 %0, %1, %2" : "=v"(d1) : "v"(hv[2]), "v"(hv[3]));
      uint2 hw; hw.x = d0; hw.y = d1;
      *(uint2*)(smem + wbbase + wroff[g]) = hw;
    }
    __syncthreads();
    if (hout) {
      int4 hv4 = *(const int4*)(smem + wbbase + wboff);
      *(int4*)(hout + wb_glob + ((size_t)t << 16)) = hv4;
    }
  }

  int fbuf = HOFF + ((T & 1) << 13);
#pragma unroll
  for (int g = 0; g < 2; ++g) {
    ushort4 hv4 = *(const ushort4*)(smem + fbuf + wroff[g]);
    int j = 16 * w + 128 * g + 4 * hi;
    u16 hb[4] = {hv4.x, hv4.y, hv4.z, hv4.w};
#pragma unroll
    for (int r = 0; r < 4; ++r) {
      h_state[(size_t)(bg + lo) * NH + j + r] = b2f(hb[r]);
      c_state[(size_t)(bg + lo) * NH + j + r] = c[g][r];
    }
  }
}

// ---------------- LayerNorm + projection -----------------------------------
__global__ __launch_bounds__(256) void ln_proj(const float* __restrict__ hn,
                                               const float* __restrict__ lng,
                                               const float* __restrict__ lnb,
                                               const float* __restrict__ pW,
                                               const float* __restrict__ pb,
                                               float* __restrict__ out) {
  __shared__ __align__(16) float nbuf[NH];
  __shared__ float red[8];
  int b = blockIdx.x, tid = threadIdx.x;
  float v = hn[(size_t)b * NH + tid];
  float s = v, s2 = v * v;
#pragma unroll
  for (int o = 32; o > 0; o >>= 1) {
    s  += __shfl_down(s, o);
    s2 += __shfl_down(s2, o);
  }
  if ((tid & 63) == 0) { red[tid >> 6] = s; red[4 + (tid >> 6)] = s2; }
  __syncthreads();
  if (tid == 0) {
    red[0] = red[0] + red[1] + red[2] + red[3];
    red[4] = red[4] + red[5] + red[6] + red[7];
  }
  __syncthreads();
  float mean = red[0] * (1.0f / NH);
  float var  = red[4] * (1.0f / NH) - mean * mean;
  float rs = rsqrtf(var + 1e-5f);
  nbuf[tid] = (v - mean) * rs * lng[tid] + lnb[tid];
  __syncthreads();
  if (tid < NE) {
    float a = pb[tid];
    const float* wr = pW + (size_t)tid * NH;
#pragma unroll 4
    for (int j = 0; j < NH; ++j) a = fmaf(nbuf[j], wr[j], a);
    out[(size_t)b * NE + tid] = a;
  }
}

// ---------------------------------------------------------------------------
extern "C" void kernel_launch(void* const* d_in, const int* in_sizes, int n_in,
                              void* d_out, int out_size, void* d_ws, size_t ws_size,
                              hipStream_t stream) {
  const int*   x     = (const int*)d_in[0];
  const float* emb   = (const float*)d_in[1];
  const float* Wih0  = (const float*)d_in[2];
  const float* Whh0  = (const float*)d_in[3];
  const float* bih0  = (const float*)d_in[4];
  const float* bhh0  = (const float*)d_in[5];
  const float* Wih1  = (const float*)d_in[6];
  const float* Whh1  = (const float*)d_in[7];
  const float* bih1  = (const float*)d_in[8];
  const float* bhh1  = (const float*)d_in[9];
  const float* ln_g  = (const float*)d_in[10];
  const float* ln_b  = (const float*)d_in[11];
  const float* projW = (const float*)d_in[12];
  const float* projb = (const float*)d_in[13];

  hipFuncSetAttribute((const void*)scan_stage,
                      hipFuncAttributeMaxDynamicSharedMemorySize, SCAN_LDS);

  // T selection: footprint = 2*xpA + xpB (T*524288 each) + iobuf (T*131072)
  const size_t FIXED = 2891776;
  int T = 64;
  while (T > 4 && FIXED + (size_t)T * 1703936 > ws_size) T >>= 1;
  int nch = NS / T;

  char* ws = (char*)d_ws;
  u16*   xpA0  = (u16*)(ws);
  u16*   xpA1  = (u16*)(ws + (size_t)T * 524288);
  u16*   xpB   = (u16*)(ws + (size_t)T * 1048576);
  u16*   iobuf = (u16*)(ws + (size_t)T * 1572864);   // e (prologue) / h1 chunk
  char*  wbase = ws + (size_t)T * 1703936;
  u16*   wih0b = (u16*)(wbase);
  u16*   whh0b = (u16*)(wbase + 262144);
  u16*   wih1b = (u16*)(wbase + 786432);
  u16*   whh1b = (u16*)(wbase + 1310720);
  float* bc0   = (float*)(wbase + 1835008);
  float* bc1   = (float*)(wbase + 1839104);
  float* hs0   = (float*)(wbase + 1843200);
  float* cs0   = (float*)(wbase + 2105344);
  float* hs1   = (float*)(wbase + 2367488);
  float* cs1   = (float*)(wbase + 2629632);
  u16*   xpA[2] = {xpA0, xpA1};

  prep_weights<<<256, 256, 0, stream>>>(Wih0, Whh0, bih0, bhh0, Wih1, Whh1, bih1, bhh1,
                                        wih0b, whh0b, wih1b, whh1b, bc0, bc1);
  // prologue: xpA[0] for L0 chunk 0
  embed_chunk<<<T * 32, 256, 0, stream>>>(x, emb, iobuf, 0);
  xp_gemm<NE><<<T * 16, 256, 0, stream>>>(iobuf, wih0b, bc0, xpA0);

  for (int s = 0; s <= nch; ++s) {
    int aA = (s < nch) ? 1 : 0;
    int aB = (s >= 1) ? 1 : 0;
    int aC = (s + 1 < nch) ? 1 : 0;
    scan_stage<<<64, 512, SCAN_LDS, stream>>>(
        xpA[s & 1], whh0b, iobuf, hs0, cs0, (s == 0) ? 1 : 0, aA,
        xpB, whh1b, hs1, cs1, (s == 1) ? 1 : 0, aB,
        x, emb, wih0b, bc0, xpA[(s + 1) & 1], (s + 1) * T, aC, T);
    if (s < nch) {
      // serial dependency: h1(s) -> xpB for L1 chunk s (consumed at stage s+1)
      xp_gemm<NH><<<T * 16, 256, 0, stream>>>(iobuf, wih1b, bc1, xpB);
    }
  }
  ln_proj<<<NB, 256, 0, stream>>>(hs1, ln_g, ln_b, projW, projb, (float*)d_out);
}